// Round 1
// baseline (223.725 us; speedup 1.0000x reference)
//
#include <hip/hip_runtime.h>
#include <hip/hip_bf16.h>
#include <cstdint>

typedef __bf16 bf16_t;
typedef __bf16 bf16x8 __attribute__((ext_vector_type(8)));
typedef float  f32x4  __attribute__((ext_vector_type(4)));

#define MFMA16(a, b, c) __builtin_amdgcn_mfma_f32_16x16x32_bf16((a), (b), (c), 0, 0, 0)

constexpr int BB = 8, CC = 384, NHH = 6, TT = 1024;

union U8 { uint4 u; bf16_t h[8]; };
union U2 { unsigned int u; bf16_t h[2]; };

// ---------------------------------------------------------------------------
// K0: normalize all inputs to canonical bf16 (inputs fp32; probe kept).
// ---------------------------------------------------------------------------
struct CastArgs {
    const void* src[9];
    bf16_t*     dst[9];
    int         n[9];
};

__global__ __launch_bounds__(256) void cast_kernel(CastArgs a)
{
    const bool isbf = (((const unsigned short*)a.src[5])[0] == 0x3F80u);
    const int ai = blockIdx.y;
    const int n  = a.n[ai];
    bf16_t* dst  = a.dst[ai];
    const int t0     = (blockIdx.x * 256 + threadIdx.x) * 8;
    const int stride = gridDim.x * 256 * 8;
    if (isbf) {
        const bf16_t* s = (const bf16_t*)a.src[ai];
        for (int idx = t0; idx < n; idx += stride) {
            if (idx + 8 <= n) *(uint4*)(dst + idx) = *(const uint4*)(s + idx);
            else for (int j = 0; idx + j < n; ++j) dst[idx + j] = s[idx + j];
        }
    } else {
        const float* s = (const float*)a.src[ai];
        for (int idx = t0; idx < n; idx += stride) {
            if (idx + 8 <= n) {
                f32x4 v0 = *(const f32x4*)(s + idx);
                f32x4 v1 = *(const f32x4*)(s + idx + 4);
                U8 o;
                #pragma unroll
                for (int j = 0; j < 4; ++j) { o.h[j] = (bf16_t)v0[j]; o.h[4 + j] = (bf16_t)v1[j]; }
                *(uint4*)(dst + idx) = o.u;
            } else for (int j = 0; idx + j < n; ++j) dst[idx + j] = (bf16_t)s[idx + j];
        }
    }
}

// ---------------------------------------------------------------------------
// K1: QKV projection.
//  q branch (og 0,1): store qT[b][t][o]  (single copy, UNSCALED - head mix
//    happens in fused_attn registers now)
//  k branch (og 2,3): store kT[b][t][o]
//  v branch (og 4,5): A=xT (D rows=t), store vm[b][o][t].
// ---------------------------------------------------------------------------
__global__ __launch_bounds__(256) void qkv_kernel(
    const bf16_t* __restrict__ x,
    const bf16_t* __restrict__ Wq,
    const bf16_t* __restrict__ Wk,
    const bf16_t* __restrict__ Wv,
    bf16_t* __restrict__ qT,
    bf16_t* __restrict__ kT,
    bf16_t* __restrict__ vm)
{
    const int og = blockIdx.x;        // 0,1:q  2,3:k  4,5:v
    const int tt = blockIdx.y;
    const int b  = blockIdx.z;
    const int t0 = tt * 64;
    const int tid  = threadIdx.x;
    const int lane = tid & 63;
    const int wid  = tid >> 6;
    const int quad = lane >> 4;
    const int l16  = lane & 15;

    __shared__ __align__(16) bf16_t xT[64][CC + 8];

    {
        const bf16_t* xb = x + (size_t)b * CC * TT;
        const int tq = tid & 7;
        const int cp = tid >> 3;
        #pragma unroll
        for (int pass = 0; pass < 6; ++pass) {
            const int c = (pass * 32 + cp) * 2;
            U8 r0, r1;
            r0.u = *(const uint4*)(xb + (size_t)c * TT + t0 + tq * 8);
            r1.u = *(const uint4*)(xb + (size_t)(c + 1) * TT + t0 + tq * 8);
            #pragma unroll
            for (int j = 0; j < 8; ++j) {
                U2 p; p.h[0] = r0.h[j]; p.h[1] = r1.h[j];
                *(unsigned int*)&xT[tq * 8 + j][c] = p.u;
            }
        }
    }
    __syncthreads();

    const bf16_t* W = (og < 2) ? Wq : (og < 4) ? Wk : Wv;
    const int obase = (og & 1) * 192 + wid * 48;

    if (og < 4) {
        // A = W rows (m=o), B = xT rows (n=t)
        f32x4 acc[3][4];
        const f32x4 zero = {0.f, 0.f, 0.f, 0.f};
        #pragma unroll
        for (int mi = 0; mi < 3; ++mi)
            #pragma unroll
            for (int ni = 0; ni < 4; ++ni) acc[mi][ni] = zero;

        for (int k0 = 0; k0 < CC; k0 += 32) {
            bf16x8 afr[3];
            #pragma unroll
            for (int mi = 0; mi < 3; ++mi)
                afr[mi] = *(const bf16x8*)(W + (size_t)(obase + mi * 16 + l16) * CC + k0 + quad * 8);
            #pragma unroll
            for (int ni = 0; ni < 4; ++ni) {
                bf16x8 bfr = *(const bf16x8*)&xT[ni * 16 + l16][k0 + quad * 8];
                #pragma unroll
                for (int mi = 0; mi < 3; ++mi)
                    acc[mi][ni] = MFMA16(afr[mi], bfr, acc[mi][ni]);
            }
        }

        bf16_t* dst = (og < 2) ? qT : kT;
        #pragma unroll
        for (int mi = 0; mi < 3; ++mi)
            #pragma unroll
            for (int ni = 0; ni < 4; ++ni) {
                const int o0 = obase + mi * 16 + quad * 4;
                const int tl = t0 + ni * 16 + l16;
                U2 lo2, hi2;
                lo2.h[0] = (bf16_t)acc[mi][ni][0]; lo2.h[1] = (bf16_t)acc[mi][ni][1];
                hi2.h[0] = (bf16_t)acc[mi][ni][2]; hi2.h[1] = (bf16_t)acc[mi][ni][3];
                uint2 pk; pk.x = lo2.u; pk.y = hi2.u;
                *(uint2*)(dst + ((size_t)b * TT + tl) * CC + o0) = pk;
            }
    } else {
        // A = xT (m=t), B = W (n=o): regs span t -> vm[o][t]
        f32x4 acc[4][3];
        const f32x4 zero = {0.f, 0.f, 0.f, 0.f};
        #pragma unroll
        for (int mi = 0; mi < 4; ++mi)
            #pragma unroll
            for (int ni = 0; ni < 3; ++ni) acc[mi][ni] = zero;

        for (int k0 = 0; k0 < CC; k0 += 32) {
            bf16x8 bfr[3];
            #pragma unroll
            for (int ni = 0; ni < 3; ++ni)
                bfr[ni] = *(const bf16x8*)(W + (size_t)(obase + ni * 16 + l16) * CC + k0 + quad * 8);
            #pragma unroll
            for (int mi = 0; mi < 4; ++mi) {
                bf16x8 afr = *(const bf16x8*)&xT[mi * 16 + l16][k0 + quad * 8];
                #pragma unroll
                for (int ni = 0; ni < 3; ++ni)
                    acc[mi][ni] = MFMA16(afr, bfr[ni], acc[mi][ni]);
            }
        }

        #pragma unroll
        for (int mi = 0; mi < 4; ++mi)
            #pragma unroll
            for (int ni = 0; ni < 3; ++ni) {
                const int ol  = obase + ni * 16 + l16;
                const int tl0 = mi * 16 + quad * 4;
                U2 lo2, hi2;
                lo2.h[0] = (bf16_t)acc[mi][ni][0]; lo2.h[1] = (bf16_t)acc[mi][ni][1];
                hi2.h[0] = (bf16_t)acc[mi][ni][2]; hi2.h[1] = (bf16_t)acc[mi][ni][3];
                uint2 pk; pk.x = lo2.u; pk.y = hi2.u;
                *(uint2*)(vm + ((size_t)b * CC + ol) * TT + t0 + tl0) = pk;
            }
    }
}

// ---------------------------------------------------------------------------
// K1b: vrs[b][g][d] = sum_t vm[b][g*64+d][t]
// ---------------------------------------------------------------------------
__global__ __launch_bounds__(256) void vrow_kernel(const bf16_t* __restrict__ vm,
                                                   float* __restrict__ vrs)
{
    const int bg = blockIdx.x;
    const int d  = threadIdx.x & 63;
    const int qr = threadIdx.x >> 6;
    const bf16_t* row = vm + ((size_t)(bg / 6) * CC + (bg % 6) * 64 + d) * TT + qr * 256;
    float s = 0.f;
    for (int i = 0; i < 256; i += 8) {
        U8 v; v.u = *(const uint4*)(row + i);
        #pragma unroll
        for (int j = 0; j < 8; ++j) s += (float)v.h[j];
    }
    __shared__ float red[4][64];
    red[qr][d] = s;
    __syncthreads();
    if (qr == 0) vrs[bg * 64 + d] = red[0][d] + red[1][d] + red[2][d] + red[3][d];
}

// ---------------------------------------------------------------------------
// K2: fused attention, per-head scores + in-register head mix.
// Block = (b = L&7 XCD-pinned, qt = 64-q tile, th = t-half of 512).
// 512 thr / 8 waves. Per 32-t tile:
//   scores: 6 segmented K=64 accumulators S_h (wave tile 16t x 16q;
//           tsub=wid&1, qh=wid>>1), Q frags persistent in 48 VGPRs.
//   mix:    M[g] = sum_h (0.125*w[g,h]) * S_h  (lane-local, 36 coeffs in
//           SGPR via readfirstlane), exp, exact l/l2 accumulation.
//   PV:     P -> LDS (bf16, swizzled), per-head PV; wave = (qg=wid>>1 16q,
//           gg=wid&1 3 heads), U[3][4] accumulators.
// LDS 96KB: Ks[6][32][64] | Ps[6][64][32] | Vs[2][384][32]; all accesses
// XOR-swizzled to <=2-way. K/V reg-staged one tile ahead (loads issued a
// full phase before ds_write). 3 barriers / tile.
// Outputs: partial U (fp32) + partial l, l2 per (th,b,g,q).
// ---------------------------------------------------------------------------
__global__ __launch_bounds__(512, 2) void fused_attn(
    const bf16_t* __restrict__ qT,
    const bf16_t* __restrict__ kT,
    const bf16_t* __restrict__ vm,
    const bf16_t* __restrict__ head_w,
    float* __restrict__ Up,      // [2][8][6][1024][64]
    float* __restrict__ lp,      // [2][48][1024]
    float* __restrict__ l2p)     // [2][48][1024]
{
    const int L  = blockIdx.x;
    const int b  = L & 7;              // XCD-pinned
    const int rr = L >> 3;
    const int qt = rr & 15;
    const int th = rr >> 4;

    const int tid = threadIdx.x, lane = tid & 63, wid = tid >> 6;
    const int quad = lane >> 4, l16 = lane & 15;

    __shared__ __align__(16) bf16_t sm[49152];   // 96 KB
    bf16_t* Ks = sm;            // [6][32][64]   24 KB
    bf16_t* Ps = sm + 12288;    // [6][64][32]   24 KB
    bf16_t* Vs = sm + 24576;    // [2][384][32]  48 KB
    __shared__ float smix[36];

    if (tid < 36) smix[tid] = 0.125f * (float)head_w[tid];

    const int T0 = th * 512;

    const int tsub = wid & 1;          // scores: K-row 16-block (0..1)
    const int sqh  = wid >> 1;         // scores: q 16-block (0..3)
    const int pqg  = wid >> 1;         // PV: q 16-block (0..3)
    const int pgg  = wid & 1;          // PV: head triple (0..1)

    // ---- persistent Q fragments (48 VGPR): row q = qt*64 + sqh*16 + l16
    bf16x8 qf[6][2];
    {
        const bf16_t* Qb = qT + ((size_t)b * TT + qt * 64 + sqh * 16 + l16) * CC + quad * 8;
        #pragma unroll
        for (int kk = 0; kk < 6; ++kk)
            #pragma unroll
            for (int k2 = 0; k2 < 2; ++k2)
                qf[kk][k2] = *(const bf16x8*)(Qb + kk * 64 + k2 * 32);
    }

    // ---- staging addressing (linear LDS dest, pre-swizzled global src)
    const bf16_t* ksrc[3]; const bf16_t* vsrc[3];
    int kdst[3], vdst[3];
    #pragma unroll
    for (int it = 0; it < 3; ++it) {
        const int f  = it * 512 + tid;
        const int kk = f >> 8, krow = (f >> 3) & 31, kch = f & 7;
        ksrc[it] = kT + ((size_t)b * TT + T0 + krow) * CC + kk * 64 + (kch ^ (krow & 7)) * 8;
        kdst[it] = f * 8;
        const int vrow = f >> 2, vch = f & 3;
        vsrc[it] = vm + ((size_t)b * CC + vrow) * TT + T0 + (vch ^ ((vrow >> 1) & 3)) * 8;
        vdst[it] = f * 8;
    }

    uint4 kreg[3], vreg[3];
    #pragma unroll
    for (int it = 0; it < 3; ++it) {   // tile 0 loads
        kreg[it] = *(const uint4*)ksrc[it];
        vreg[it] = *(const uint4*)vsrc[it];
    }
    __syncthreads();                   // smix visible

    float mixc[36];
    #pragma unroll
    for (int j = 0; j < 36; ++j)
        mixc[j] = __uint_as_float(__builtin_amdgcn_readfirstlane(__float_as_uint(smix[j])));

    #pragma unroll
    for (int it = 0; it < 3; ++it) {   // write tile 0; load tile 1
        *(uint4*)&Ks[kdst[it]] = kreg[it];
        *(uint4*)&Vs[vdst[it]] = vreg[it];
        kreg[it] = *(const uint4*)(ksrc[it] + 32 * CC);
        vreg[it] = *(const uint4*)(vsrc[it] + 32);
    }
    __syncthreads();                   // tile 0 staged

    f32x4 Uacc[3][4];
    const f32x4 zero = {0.f, 0.f, 0.f, 0.f};
    #pragma unroll
    for (int hh = 0; hh < 3; ++hh)
        #pragma unroll
        for (int n2 = 0; n2 < 4; ++n2) Uacc[hh][n2] = zero;
    float lacc[6]  = {0.f, 0.f, 0.f, 0.f, 0.f, 0.f};
    float l2acc[6] = {0.f, 0.f, 0.f, 0.f, 0.f, 0.f};

    const int arow  = (tsub * 16 + l16) * 64;
    const int aswz0 = ((quad)     ^ (l16 & 7)) * 8;
    const int aswz1 = ((4 + quad) ^ (l16 & 7)) * 8;
    const int prow  = (sqh * 16 + l16) * 32;
    const int pswzW = ((tsub * 2 + (quad >> 1)) ^ ((l16 >> 1) & 3)) * 8 + (quad & 1) * 4;
    const int parow = (pqg * 16 + l16) * 32;
    const int pswzR = (quad ^ ((l16 >> 1) & 3)) * 8;

    for (int t = 0; t < 16; ++t) {
        // ---- per-head score tiles: S_h^T (t = tsub*16+quad*4+r, q = sqh*16+l16)
        f32x4 S[6];
        #pragma unroll
        for (int kk = 0; kk < 6; ++kk) {
            bf16x8 a0 = *(const bf16x8*)&Ks[kk * 2048 + arow + aswz0];
            bf16x8 a1 = *(const bf16x8*)&Ks[kk * 2048 + arow + aswz1];
            S[kk] = MFMA16(a0, qf[kk][0], zero);
            S[kk] = MFMA16(a1, qf[kk][1], S[kk]);
        }
        // ---- head mix (fp32, lane-local) + exp + l/l2 + bf16 pack
        uint2 pk[6];
        #pragma unroll
        for (int g = 0; g < 6; ++g) {
            float mp[4];
            #pragma unroll
            for (int r = 0; r < 4; ++r) {
                float m = mixc[g * 6] * S[0][r];
                #pragma unroll
                for (int h = 1; h < 6; ++h) m += mixc[g * 6 + h] * S[h][r];
                const float p = __expf(fminf(m, 60.0f));
                lacc[g]  += p;
                l2acc[g] += p * p;
                mp[r] = p;
            }
            U2 lo, hi;
            lo.h[0] = (bf16_t)mp[0]; lo.h[1] = (bf16_t)mp[1];
            hi.h[0] = (bf16_t)mp[2]; hi.h[1] = (bf16_t)mp[3];
            pk[g].x = lo.u; pk[g].y = hi.u;
        }
        __syncthreads();   // B1: all K_t reads done
        #pragma unroll
        for (int it = 0; it < 3; ++it) {               // stage tile t+1
            *(uint4*)&Ks[kdst[it]] = kreg[it];
            *(uint4*)&Vs[((t + 1) & 1) * 12288 + vdst[it]] = vreg[it];
        }
        #pragma unroll
        for (int g = 0; g < 6; ++g)                    // P_t -> LDS
            *(uint2*)&Ps[g * 2048 + prow + pswzW] = pk[g];
        {                                              // issue loads tile t+2
            const int nt = ((t + 2) & 15) * 32;
            #pragma unroll
            for (int it = 0; it < 3; ++it) {
                kreg[it] = *(const uint4*)(ksrc[it] + nt * CC);
                vreg[it] = *(const uint4*)(vsrc[it] + nt);
            }
        }
        __syncthreads();   // B2: P_t + staged tile t+1 visible
        // ---- PV: U[q][d] += P[q][t] * V[d][t]
        const int vb = (t & 1) * 12288;
        #pragma unroll
        for (int hh = 0; hh < 3; ++hh) {
            const int g = pgg * 3 + hh;
            bf16x8 ap = *(const bf16x8*)&Ps[g * 2048 + parow + pswzR];
            #pragma unroll
            for (int n2 = 0; n2 < 4; ++n2) {
                bf16x8 bv = *(const bf16x8*)&Vs[vb + (g * 64 + n2 * 16 + l16) * 32 + pswzR];
                Uacc[hh][n2] = MFMA16(ap, bv, Uacc[hh][n2]);
            }
        }
        __syncthreads();   // B3: P_t / V_t reads done
    }

    // ---- l / l2 partial reduction (per g, q)
    float* lredL  = (float*)sm;            // alias, region dead
    float* l2redL = lredL + 768;
    #pragma unroll
    for (int g = 0; g < 6; ++g) {
        float l = lacc[g], l2 = l2acc[g];
        l  += __shfl_xor(l, 16, 64);  l  += __shfl_xor(l, 32, 64);
        l2 += __shfl_xor(l2, 16, 64); l2 += __shfl_xor(l2, 32, 64);
        if (quad == 0) {
            lredL [wid * 96 + g * 16 + l16] = l;
            l2redL[wid * 96 + g * 16 + l16] = l2;
        }
    }
    __syncthreads();
    if (tid < 384) {
        const int g = tid >> 6, q = tid & 63;
        const int w0 = (q >> 4) * 2, lo = q & 15;
        const float l  = lredL [w0 * 96 + g * 16 + lo] + lredL [(w0 + 1) * 96 + g * 16 + lo];
        const float l2 = l2redL[w0 * 96 + g * 16 + lo] + l2redL[(w0 + 1) * 96 + g * 16 + lo];
        const size_t o = ((size_t)th * 48 + b * 6 + g) * TT + qt * 64 + q;
        lp[o] = l; l2p[o] = l2;
    }

    // ---- partial U write (fp32, [th][b][g][q][d])
    #pragma unroll
    for (int hh = 0; hh < 3; ++hh) {
        const int g = pgg * 3 + hh;
        float* Ub = Up + ((((size_t)th * 8 + b) * 6 + g) * TT + qt * 64 + pqg * 16) * 64;
        #pragma unroll
        for (int n2 = 0; n2 < 4; ++n2)
            #pragma unroll
            for (int r = 0; r < 4; ++r)
                Ub[(size_t)(quad * 4 + r) * 64 + n2 * 16 + l16] = Uacc[hh][n2][r];
    }
}

// ---------------------------------------------------------------------------
// K2b: merge t-half partials: linv[bg][q] = 1/(l0+l1),
//      sq[bg] = sum_q (l2_0+l2_1)/(l0+l1)^2   (no atomics)
// ---------------------------------------------------------------------------
__global__ __launch_bounds__(256) void stats_kernel(
    const float* __restrict__ lp, const float* __restrict__ l2p,
    float* __restrict__ linv, float* __restrict__ sq)
{
    const int bg = blockIdx.x, tid = threadIdx.x;
    float c = 0.f;
    for (int q = tid; q < TT; q += 256) {
        const float l  = lp [(size_t)bg * TT + q] + lp [(size_t)(48 + bg) * TT + q];
        const float l2 = l2p[(size_t)bg * TT + q] + l2p[(size_t)(48 + bg) * TT + q];
        const float inv = 1.0f / l;
        linv[bg * TT + q] = inv;
        c += l2 * inv * inv;
    }
    #pragma unroll
    for (int off = 1; off < 64; off <<= 1) c += __shfl_xor(c, off, 64);
    __shared__ float red[4];
    if ((tid & 63) == 0) red[tid >> 6] = c;
    __syncthreads();
    if (tid == 0) sq[bg] = red[0] + red[1] + red[2] + red[3];
}

// ---------------------------------------------------------------------------
// K3: projection + fused InstanceNorm affine + bias + transpose.
//   Z[t'][c'] = Ac[h]*( (U0[off]+U1[off]) * linv[row] ) + Cc[h]*vrs[h][d]
//   off = t'*384 + c'; row = off>>6 = g*1024+q; h = off>>16; d = off&63.
// ---------------------------------------------------------------------------
__global__ __launch_bounds__(256) void proj_kernel(
    const float* __restrict__ Up,
    const float* __restrict__ linv,
    const float* __restrict__ vrs,
    const float* __restrict__ sumsq,
    const bf16_t* __restrict__ gamma,
    const bf16_t* __restrict__ beta,
    const bf16_t* __restrict__ projW,
    const bf16_t* __restrict__ projb,
    float* __restrict__ out)
{
    const int ts = blockIdx.x;
    const int b  = blockIdx.y;
    const int t0 = ts * 32;
    const int tid = threadIdx.x, lane = tid & 63, wid = tid >> 6;
    const int quad = lane >> 4, l16 = lane & 15;

    __shared__ float Ac[6], Cc[6], pb[CC];
    if (tid < 6) {
        const float ss  = sumsq[b * NHH + tid];
        const float var = fmaxf(ss - 1.0f, 0.0f) * (1.0f / 1048576.0f);
        const float a   = (float)gamma[tid] * rsqrtf(var + 1e-5f);
        Ac[tid] = a;
        Cc[tid] = (float)beta[tid] - a * (1.0f / 1024.0f);
    }
    for (int i = tid; i < CC; i += 256) pb[i] = (float)projb[i];
    __syncthreads();

    f32x4 acc[6][2];
    const f32x4 zero = {0.f, 0.f, 0.f, 0.f};
    #pragma unroll
    for (int mi = 0; mi < 6; ++mi)
        #pragma unroll
        for (int ni = 0; ni < 2; ++ni) acc[mi][ni] = zero;

    const float* U0 = Up + (size_t)b * (NHH * TT * 64);
    const float* U1 = Up + (size_t)(8 + b) * (NHH * TT * 64);
    for (int k0 = 0; k0 < CC; k0 += 32) {
        bf16x8 bfr[2];
        #pragma unroll
        for (int ni = 0; ni < 2; ++ni) {
            const int tl = t0 + ni * 16 + l16;
            const int baseoff = tl * CC + k0 + quad * 8;
            const int hh = baseoff >> 16;                 // constant over j (no 64-crossing)
            const float li = linv[b * 6144 + (baseoff >> 6)];
            const float A  = Ac[hh];
            const float Cb = Cc[hh];
            f32x4 a0 = *(const f32x4*)(U0 + baseoff);
            f32x4 a1 = *(const f32x4*)(U0 + baseoff + 4);
            f32x4 c0 = *(const f32x4*)(U1 + baseoff);
            f32x4 c1 = *(const f32x4*)(U1 + baseoff + 4);
            U8 z;
            #pragma unroll
            for (int j = 0; j < 8; ++j) {
                const int d = (baseoff + j) & 63;
                const float uv = ((j < 4) ? (a0[j] + c0[j]) : (a1[j - 4] + c1[j - 4])) * li;
                z.h[j] = (bf16_t)(A * uv + Cb * vrs[(b * NHH + hh) * 64 + d]);
            }
            bfr[ni] = *(const bf16x8*)&z;
        }
        #pragma unroll
        for (int mi = 0; mi < 6; ++mi) {
            const int o = wid * 96 + mi * 16 + l16;
            bf16x8 afr = *(const bf16x8*)(projW + (size_t)o * CC + k0 + quad * 8);
            #pragma unroll
            for (int ni = 0; ni < 2; ++ni)
                acc[mi][ni] = MFMA16(afr, bfr[ni], acc[mi][ni]);
        }
    }

    #pragma unroll
    for (int mi = 0; mi < 6; ++mi)
        #pragma unroll
        for (int ni = 0; ni < 2; ++ni)
            #pragma unroll
            for (int r = 0; r < 4; ++r) {
                const int o  = wid * 96 + mi * 16 + quad * 4 + r;
                const int tl = t0 + ni * 16 + l16;
                out[((size_t)b * CC + o) * TT + tl] = acc[mi][ni][r] + pb[o];
            }
}

// ---------------------------------------------------------------------------
extern "C" void kernel_launch(void* const* d_in, const int* in_sizes, int n_in,
                              void* d_out, int out_size, void* d_ws, size_t ws_size,
                              hipStream_t stream)
{
    float* outp = (float*)d_out;
    char* ws = (char*)d_ws;

    size_t off = 0;
    auto alloc = [&](size_t bytes) {
        void* p = ws + off;
        off += (bytes + 255) & ~(size_t)255;
        return p;
    };

    const size_t szT = (size_t)BB * TT * CC * sizeof(bf16_t);   // 6.29 MB

    bf16_t* cx  = (bf16_t*)alloc(szT);
    bf16_t* cWq = (bf16_t*)alloc((size_t)CC * CC * 2);
    bf16_t* cWk = (bf16_t*)alloc((size_t)CC * CC * 2);
    bf16_t* cWv = (bf16_t*)alloc((size_t)CC * CC * 2);
    bf16_t* cPW = (bf16_t*)alloc((size_t)CC * CC * 2);
    bf16_t* chw = (bf16_t*)alloc(64 * 2);
    bf16_t* cg  = (bf16_t*)alloc(64 * 2);
    bf16_t* cb  = (bf16_t*)alloc(64 * 2);
    bf16_t* cpb = (bf16_t*)alloc(CC * 2);
    bf16_t* qTb = (bf16_t*)alloc(szT);
    bf16_t* kTb = (bf16_t*)alloc(szT);
    bf16_t* vmb = (bf16_t*)alloc(szT);
    float*  Uh  = (float*)alloc((size_t)2 * BB * NHH * TT * 64 * sizeof(float)); // 25.2 MB
    float*  lpb = (float*)alloc((size_t)2 * 48 * TT * sizeof(float));
    float*  l2b = (float*)alloc((size_t)2 * 48 * TT * sizeof(float));
    float*  lv  = (float*)alloc((size_t)48 * TT * sizeof(float));
    float*  vr  = (float*)alloc(48 * 64 * sizeof(float));
    float*  sq  = (float*)alloc(48 * sizeof(float));

    CastArgs ca;
    bf16_t* dsts[9] = {cx, cWq, cWk, cWv, chw, cg, cb, cPW, cpb};
    for (int i = 0; i < 9; ++i) {
        ca.src[i] = d_in[i];
        ca.dst[i] = dsts[i];
        ca.n[i]   = in_sizes[i];
    }

    cast_kernel<<<dim3(192, 9), 256, 0, stream>>>(ca);
    qkv_kernel<<<dim3(6, 16, 8), 256, 0, stream>>>(cx, cWq, cWk, cWv, qTb, kTb, vmb);
    vrow_kernel<<<48, 256, 0, stream>>>(vmb, vr);
    fused_attn<<<256, 512, 0, stream>>>(qTb, kTb, vmb, chw, Uh, lpb, l2b);
    stats_kernel<<<48, 256, 0, stream>>>(lpb, l2b, lv, sq);
    proj_kernel<<<dim3(32, 8), 256, 0, stream>>>(Uh, lv, vr, sq, cg, cb, cPW, cpb, outp);
}